// Round 5
// baseline (89.173 us; speedup 1.0000x reference)
//
#include <hip/hip_runtime.h>
#include <hip/hip_bf16.h>

#define NCLS 13
#define ROWS 32                          // rows per tile
#define BLOCK 256                        // 4 waves, 8 threads per row
#define TPB 4                            // tiles per block
#define C_FLOATS (ROWS * NCLS * NCLS)    // 5408
#define XS_FLOATS (ROWS * NCLS)          // 416
#define C_F4 (C_FLOATS / 4)              // 1352
#define XS_F4 (XS_FLOATS / 4)            // 104

__global__ __launch_bounds__(BLOCK) void rnorm_kernel(
    const float* __restrict__ input,
    const int* __restrict__ target,
    const float* __restrict__ s,
    const float* __restrict__ C,
    float* __restrict__ out,
    int ntiles)
{
    // single-buffered LDS (~25 KB) -> 6 blocks/CU resident
    __shared__ __align__(16) float cb[C_FLOATS];
    __shared__ __align__(16) float xb[XS_FLOATS];
    __shared__ __align__(16) float sb[XS_FLOATS];
    __shared__ float wsum[4];

    const int tid = threadIdx.x;
    const int row = tid >> 3;   // 0..31
    const int q   = tid & 7;    // 8 threads per row

    const int tile0 = blockIdx.x * TPB;
    const int nt = min(TPB, ntiles - tile0);
    float res_acc = 0.0f;

    // register staging for the next tile (T14: issue early, write late)
    float4 creg[6];
    float4 xsreg = make_float4(0.f, 0.f, 0.f, 0.f);
    int treg = 0;

    auto issue_loads = [&](int tile) {
        const float4* Cg = (const float4*)(C + (size_t)tile * C_FLOATS);
#pragma unroll
        for (int m = 0; m < 6; ++m) {
            const int k = m * BLOCK + tid;
            if (m < 5 || k < C_F4) creg[m] = Cg[k];
        }
        if (tid < XS_F4)
            xsreg = ((const float4*)(input + (size_t)tile * XS_FLOATS))[tid];
        else if (tid >= 128 && tid < 128 + XS_F4)
            xsreg = ((const float4*)(s + (size_t)tile * XS_FLOATS))[tid - 128];
        treg = target[tile * ROWS + row];
        asm volatile("" ::: "memory");   // keep loads issued here, not sunk below compute
    };
    auto write_lds = [&]() {             // compiler inserts the vmcnt wait before these
#pragma unroll
        for (int m = 0; m < 6; ++m) {
            const int k = m * BLOCK + tid;
            if (m < 5 || k < C_F4) ((float4*)cb)[k] = creg[m];
        }
        if (tid < XS_F4) ((float4*)xb)[tid] = xsreg;
        else if (tid >= 128 && tid < 128 + XS_F4) ((float4*)sb)[tid - 128] = xsreg;
    };

    if (nt > 0) {
        // prologue: stage tile 0
        issue_loads(tile0);
        write_lds();
        __syncthreads();
        int t_cur = treg;

        for (int t = 0; t < nt; ++t) {
            // issue next tile's global loads; latency hides under compute below
            if (t + 1 < nt) issue_loads(tile0 + t + 1);

            // ---- compute tile t from LDS ----
            float xr[NCLS];
#pragma unroll
            for (int j = 0; j < NCLS; ++j) xr[j] = xb[row * NCLS + j];

            const float* crow = cb + row * (NCLS * NCLS);
            float sp = 0.0f, sy = 0.0f, dd = 0.0f;

#pragma unroll
            for (int rep = 0; rep < 2; ++rep) {
                const int i = q + rep * 8;           // covers i = 0..12 across the 8-group
                if (rep == 0 || q < 5) {
                    float zye = 0.0f;
#pragma unroll
                    for (int j = 0; j < NCLS; ++j)
                        zye = fmaf(crow[i * NCLS + j], xr[j], zye);
                    const float zpe = crow[i * NCLS + t_cur];  // one-hot column = direct read
                    const float svi = sb[row * NCLS + i];
                    const float zp = svi - zpe, zy = svi - zye;
                    sp = fmaf(zp, zp, sp);
                    sy = fmaf(zy, zy, sy);
                    dd = fmaf(zy, zp, dd);
                }
            }

            // reduce across the 8-lane row group
            sp += __shfl_xor(sp, 1); sp += __shfl_xor(sp, 2); sp += __shfl_xor(sp, 4);
            sy += __shfl_xor(sy, 1); sy += __shfl_xor(sy, 2); sy += __shfl_xor(sy, 4);
            dd += __shfl_xor(dd, 1); dd += __shfl_xor(dd, 2); dd += __shfl_xor(dd, 4);

            if (q == 0)
                res_acc += sqrtf(sp) - dd / sqrtf(sy);

            if (t + 1 < nt) {
                __syncthreads();   // everyone done reading LDS tile t
                write_lds();       // regs -> LDS (waits on the global loads here)
                __syncthreads();   // LDS tile t+1 visible
                t_cur = treg;
            }
        }
    }

    // ---- block reduction ----
#pragma unroll
    for (int off = 32; off > 0; off >>= 1)
        res_acc += __shfl_down(res_acc, off, 64);

    const int lane = tid & 63;
    const int wid  = tid >> 6;
    if (lane == 0) wsum[wid] = res_acc;
    __syncthreads();
    if (tid == 0)
        atomicAdd(out, wsum[0] + wsum[1] + wsum[2] + wsum[3]);
}

extern "C" void kernel_launch(void* const* d_in, const int* in_sizes, int n_in,
                              void* d_out, int out_size, void* d_ws, size_t ws_size,
                              hipStream_t stream) {
    const float* input  = (const float*)d_in[0];
    const int*   target = (const int*)d_in[1];   // harness passes integers as int32
    const float* s      = (const float*)d_in[2];
    const float* C      = (const float*)d_in[3];
    // d_in[4] (instance_weights) is unused by the reference.

    float* out = (float*)d_out;
    int N = in_sizes[1];

    // harness poisons d_out and does not re-zero between replays
    hipMemsetAsync(out, 0, sizeof(float) * out_size, stream);

    const int ntiles = N / ROWS;                        // 8192
    const int grid = (ntiles + TPB - 1) / TPB;          // 2048
    rnorm_kernel<<<grid, BLOCK, 0, stream>>>(input, target, s, C, out, ntiles);
}

// Round 6
// 60.164 us; speedup vs baseline: 1.4822x; 1.4822x over previous
//
#include <hip/hip_runtime.h>
#include <hip/hip_bf16.h>

#define NCLS 13
#define ROWS 16                          // rows per tile
#define BLOCK 256                        // 4 waves, 16 threads per row
#define TPB 8                            // tiles per block
#define C_FLOATS (ROWS * NCLS * NCLS)    // 2704 floats
#define XS_FLOATS (ROWS * NCLS)          // 208 floats
#define C_F4 (C_FLOATS / 4)              // 676
#define XS_F4 (XS_FLOATS / 4)            // 52

// async global->LDS, 16B per lane; dest must be wave-uniform base + lane*16
__device__ __forceinline__ void async_cp16(const float* g, float* l) {
    __builtin_amdgcn_global_load_lds(
        (__attribute__((address_space(1))) void*)(const_cast<float*>(g)),
        (__attribute__((address_space(3))) void*)(l),
        16, 0, 0);
}

__device__ __forceinline__ void stage_tile(float* cb, float* xb, float* sb,
                                           const float* __restrict__ C,
                                           const float* __restrict__ input,
                                           const float* __restrict__ s,
                                           int tile, int tid) {
    const float* Cg = C + (size_t)tile * C_FLOATS;
    // 676 float4s: chunks of 256, 256, 164
    async_cp16(Cg + (size_t)tid * 4,         cb + (size_t)tid * 4);
    async_cp16(Cg + (size_t)(tid + 256) * 4, cb + (size_t)(tid + 256) * 4);
    if (tid < C_F4 - 512)
        async_cp16(Cg + (size_t)(tid + 512) * 4, cb + (size_t)(tid + 512) * 4);
    if (tid < XS_F4)
        async_cp16(input + (size_t)tile * XS_FLOATS + (size_t)tid * 4,
                   xb + (size_t)tid * 4);
    else if (tid >= 64 && tid < 64 + XS_F4)
        async_cp16(s + (size_t)tile * XS_FLOATS + (size_t)(tid - 64) * 4,
                   sb + (size_t)(tid - 64) * 4);
}

__global__ __launch_bounds__(BLOCK) void rnorm_kernel(
    const float* __restrict__ input,
    const int* __restrict__ target,
    const float* __restrict__ s,
    const float* __restrict__ C,
    float* __restrict__ out,
    int ntiles)
{
    // double-buffered LDS: 2*(2704+208+208)*4 = 24960 B -> 6 blocks/CU
    __shared__ __align__(16) float cbuf[2][C_FLOATS];
    __shared__ __align__(16) float xbuf[2][XS_FLOATS];
    __shared__ __align__(16) float sbuf[2][XS_FLOATS];
    __shared__ float wsum[4];

    const int tid = threadIdx.x;
    const int row = tid >> 4;   // 0..15
    const int q   = tid & 15;   // 16 threads per row, 13 active

    const int tile0 = blockIdx.x * TPB;
    const int nt = min(TPB, ntiles - tile0);
    float res_acc = 0.0f;

    if (nt > 0) {
        // prologue: stage tile 0
        stage_tile(cbuf[0], xbuf[0], sbuf[0], C, input, s, tile0, tid);
        int t_cur = target[tile0 * ROWS + row];
        asm volatile("s_waitcnt vmcnt(0)" ::: "memory");
        __syncthreads();

        for (int t = 0; t < nt; ++t) {
            const int cur = t & 1;
            const float* cb = cbuf[cur];
            const float* xb = xbuf[cur];
            const float* sb = sbuf[cur];

            int t_next = 0;
            if (t + 1 < nt) {
                stage_tile(cbuf[cur ^ 1], xbuf[cur ^ 1], sbuf[cur ^ 1],
                           C, input, s, tile0 + t + 1, tid);
                t_next = target[(tile0 + t + 1) * ROWS + row];
            }

            // ---- compute tile t from LDS: lane q handles i=q (q<13) ----
            float sp = 0.0f, sy = 0.0f, dd = 0.0f;
            if (q < NCLS) {
                const float* crow = cb + row * (NCLS * NCLS) + q * NCLS;
                const float* xrow = xb + row * NCLS;
                float zye = 0.0f;
#pragma unroll
                for (int j = 0; j < NCLS; ++j)
                    zye = fmaf(crow[j], xrow[j], zye);
                const float zpe = crow[t_cur];          // one-hot column
                const float svi = sb[row * NCLS + q];
                const float zp = svi - zpe, zy = svi - zye;
                sp = zp * zp;
                sy = zy * zy;
                dd = zy * zp;
            }

            // reduce across the 16-lane row group
            sp += __shfl_xor(sp, 1); sp += __shfl_xor(sp, 2);
            sp += __shfl_xor(sp, 4); sp += __shfl_xor(sp, 8);
            sy += __shfl_xor(sy, 1); sy += __shfl_xor(sy, 2);
            sy += __shfl_xor(sy, 4); sy += __shfl_xor(sy, 8);
            dd += __shfl_xor(dd, 1); dd += __shfl_xor(dd, 2);
            dd += __shfl_xor(dd, 4); dd += __shfl_xor(dd, 8);

            if (q == 0)
                res_acc += sqrtf(sp) - dd / sqrtf(sy);

            if (t + 1 < nt) {
                // drain this wave's async loads for tile t+1, then barrier
                asm volatile("s_waitcnt vmcnt(0)" ::: "memory");
                __syncthreads();
                t_cur = t_next;
            }
        }
    }

    // ---- block reduction ----
#pragma unroll
    for (int off = 32; off > 0; off >>= 1)
        res_acc += __shfl_down(res_acc, off, 64);

    const int lane = tid & 63;
    const int wid  = tid >> 6;
    if (lane == 0) wsum[wid] = res_acc;
    __syncthreads();
    if (tid == 0)
        atomicAdd(out, wsum[0] + wsum[1] + wsum[2] + wsum[3]);
}

extern "C" void kernel_launch(void* const* d_in, const int* in_sizes, int n_in,
                              void* d_out, int out_size, void* d_ws, size_t ws_size,
                              hipStream_t stream) {
    const float* input  = (const float*)d_in[0];
    const int*   target = (const int*)d_in[1];   // harness passes integers as int32
    const float* s      = (const float*)d_in[2];
    const float* C      = (const float*)d_in[3];
    // d_in[4] (instance_weights) is unused by the reference.

    float* out = (float*)d_out;
    int N = in_sizes[1];

    // harness poisons d_out and does not re-zero between replays
    hipMemsetAsync(out, 0, sizeof(float) * out_size, stream);

    const int ntiles = N / ROWS;                 // 16384
    const int grid = (ntiles + TPB - 1) / TPB;   // 2048
    rnorm_kernel<<<grid, BLOCK, 0, stream>>>(input, target, s, C, out, ntiles);
}

// Round 8
// 50.830 us; speedup vs baseline: 1.7543x; 1.1836x over previous
//
#include <hip/hip_runtime.h>
#include <hip/hip_bf16.h>

#define NCLS 13
#define ROWS 16                          // rows per tile
#define BLOCK 256                        // 4 waves; wave w owns rows 4w..4w+3
#define TPB 16                           // tiles per block
#define NBUF 3                           // triple buffer, 2-deep prefetch
#define C_FLOATS (ROWS * NCLS * NCLS)    // 2704 floats (10816 B)
#define XS_FLOATS (ROWS * NCLS)          // 208 floats
#define CW 676                           // C floats per wave (4 rows * 169)
#define CW4 169                          // C float4s per wave

// async global->LDS DMA, 16B/lane; HW writes LDS at uniform base + lane*16
__device__ __forceinline__ void async_cp16(const float* g, float* l) {
    __builtin_amdgcn_global_load_lds(
        (__attribute__((address_space(1))) void*)(const_cast<float*>(g)),
        (__attribute__((address_space(3))) void*)(l),
        16, 0, 0);
}

__global__ __launch_bounds__(BLOCK) void rnorm_kernel(
    const float* __restrict__ input,
    const int* __restrict__ target,
    const float* __restrict__ s,
    const float* __restrict__ C,
    float* __restrict__ out,
    int ntiles)
{
    // 3 * (10816 + 832 + 832 + 64) B ≈ 36.8 KB -> 4 blocks/CU
    __shared__ __align__(16) float cb[NBUF][C_FLOATS];
    __shared__ __align__(16) float xb[NBUF][XS_FLOATS];
    __shared__ __align__(16) float sb[NBUF][XS_FLOATS];
    __shared__ __align__(16) int   tb[NBUF][ROWS];
    __shared__ float wsum[4];

    const int tid  = threadIdx.x;
    const int w    = tid >> 6;    // wave 0..3
    const int lane = tid & 63;
    const int row  = tid >> 4;    // 0..15
    const int q    = tid & 15;    // 16 lanes per row, 13 active

    const int tile0 = blockIdx.x * TPB;
    const int nt = min(TPB, ntiles - tile0);
    float res_acc = 0.0f;

    // Per wave per stage: 3 C-chunk DMAs + 1 aux DMA = 4 vmem ops.
    // All addresses in float4 units (1 float4 = 16 B = one lane's DMA).
    auto stage = [&](int t_idx, int buf) {
        const int tile = tile0 + t_idx;
        const float4* Cg = (const float4*)(C + (size_t)tile * C_FLOATS) + w * CW4;
        float* cd = &cb[buf][w * CW];
        // float4 chunk indices: [0,64), [64,128), [128,169)
        async_cp16((const float*)(Cg + lane),       cd + (size_t)lane * 4);
        async_cp16((const float*)(Cg + 64 + lane),  cd + (size_t)(64 + lane) * 4);
        if (lane < CW4 - 128)
            async_cp16((const float*)(Cg + 128 + lane), cd + (size_t)(128 + lane) * 4);
        if (w == 0) {
            const float4* xg = (const float4*)(input + (size_t)tile * XS_FLOATS);
            if (lane < XS_FLOATS / 4)
                async_cp16((const float*)(xg + lane), &xb[buf][0] + (size_t)lane * 4);
        } else if (w == 1) {
            const float4* sg = (const float4*)(s + (size_t)tile * XS_FLOATS);
            if (lane < XS_FLOATS / 4)
                async_cp16((const float*)(sg + lane), &sb[buf][0] + (size_t)lane * 4);
        } else {  // waves 2 and 3 both stage targets (identical data, benign)
            if (lane < ROWS / 4)
                async_cp16((const float*)(target + (size_t)tile * ROWS) + (size_t)lane * 4,
                           (float*)&tb[buf][0] + (size_t)lane * 4);
        }
    };

    if (nt > 0) {
        stage(0, 0);
        if (nt > 1) {
            stage(1, 1);
            asm volatile("s_waitcnt vmcnt(4)" ::: "memory");
        } else {
            asm volatile("s_waitcnt vmcnt(0)" ::: "memory");
        }
        __builtin_amdgcn_s_barrier();

        int bcur = 0;
        for (int t = 0; t < nt; ++t) {
            // issue tile t+2 (stays in flight across the barrier below)
            if (t + 2 < nt) {
                int bpre = bcur + 2; if (bpre >= NBUF) bpre -= NBUF;
                stage(t + 2, bpre);
            }

            // ---- compute tile t from LDS ----
            const float* cbt = cb[bcur];
            const float* xbt = xb[bcur];
            const float* sbt = sb[bcur];
            const int tt = tb[bcur][row];

            float sp = 0.0f, sy = 0.0f, dd = 0.0f;
            if (q < NCLS) {
                const float* crow = cbt + row * (NCLS * NCLS) + q * NCLS;
                const float* xrow = xbt + row * NCLS;
                float zye = 0.0f;
#pragma unroll
                for (int j = 0; j < NCLS; ++j)
                    zye = fmaf(crow[j], xrow[j], zye);
                const float zpe = crow[tt];            // one-hot column
                const float svi = sbt[row * NCLS + q];
                const float zp = svi - zpe, zy = svi - zye;
                sp = zp * zp; sy = zy * zy; dd = zy * zp;
            }

            sp += __shfl_xor(sp, 1); sp += __shfl_xor(sp, 2);
            sp += __shfl_xor(sp, 4); sp += __shfl_xor(sp, 8);
            sy += __shfl_xor(sy, 1); sy += __shfl_xor(sy, 2);
            sy += __shfl_xor(sy, 4); sy += __shfl_xor(sy, 8);
            dd += __shfl_xor(dd, 1); dd += __shfl_xor(dd, 2);
            dd += __shfl_xor(dd, 4); dd += __shfl_xor(dd, 8);

            if (q == 0)
                res_acc += sqrtf(sp) - dd / sqrtf(sy);

            if (t + 1 < nt) {
                // counted wait: tile t+1 landed; tile t+2 stays in flight.
                if (t + 2 < nt) asm volatile("s_waitcnt vmcnt(4)" ::: "memory");
                else            asm volatile("s_waitcnt vmcnt(0)" ::: "memory");
                __builtin_amdgcn_s_barrier();   // raw barrier: no implicit drain
            }
            bcur = (bcur + 1 == NBUF) ? 0 : bcur + 1;
        }
    }

    // ---- block reduction ----
#pragma unroll
    for (int off = 32; off > 0; off >>= 1)
        res_acc += __shfl_down(res_acc, off, 64);

    if (lane == 0) wsum[w] = res_acc;
    __syncthreads();
    if (tid == 0)
        atomicAdd(out, wsum[0] + wsum[1] + wsum[2] + wsum[3]);
}

extern "C" void kernel_launch(void* const* d_in, const int* in_sizes, int n_in,
                              void* d_out, int out_size, void* d_ws, size_t ws_size,
                              hipStream_t stream) {
    const float* input  = (const float*)d_in[0];
    const int*   target = (const int*)d_in[1];   // harness passes integers as int32
    const float* s      = (const float*)d_in[2];
    const float* C      = (const float*)d_in[3];
    // d_in[4] (instance_weights) is unused by the reference.

    float* out = (float*)d_out;
    int N = in_sizes[1];

    // harness poisons d_out and does not re-zero between replays
    hipMemsetAsync(out, 0, sizeof(float) * out_size, stream);

    const int ntiles = N / ROWS;                 // 16384
    const int grid = (ntiles + TPB - 1) / TPB;   // 1024 = 4 blocks/CU
    rnorm_kernel<<<grid, BLOCK, 0, stream>>>(input, target, s, C, out, ntiles);
}